// Round 6
// baseline (62.606 us; speedup 1.0000x reference)
//
#include <hip/hip_runtime.h>

// Problem constants (match reference): B=64, N=10000, D=128, F=4
#define PB 64
#define PN 10000
#define PD 128
#define PF 4
#define S_SLICES 32  // partial-sum slices over N; ws needs 32*64*128*4 = 1 MB

typedef float f4v __attribute__((ext_vector_type(4)));

// ---------------------------------------------------------------------------
// Kernel 1: partial mean-sum over N slices.
// grid = (B, S), block = 256. Thread t: d4 = t&31 (float4 column), r0 = t>>5
// (row phase 0..7). 6 independent 16B loads in flight per thread.
// PLAIN loads (no nontemporal): H is re-read every replay and ~2/3 of it can
// stay L3-resident under LRU; nt marked it evict-first and capped retention.
// ---------------------------------------------------------------------------
__global__ __launch_bounds__(256) void partial_sum_kernel(
    const float* __restrict__ H, float* __restrict__ partial,
    int rows_per_slice) {
  const int b = blockIdx.x;
  const int s = blockIdx.y;
  const int t = threadIdx.x;
  const int d4 = t & 31;
  const int r0 = t >> 5;

  const int n_begin = s * rows_per_slice;
  int n_end = n_begin + rows_per_slice;
  if (n_end > PN) n_end = PN;

  const f4v* __restrict__ Hb =
      reinterpret_cast<const f4v*>(H) + (size_t)b * PN * (PD / 4);

  f4v a0 = (f4v)(0.f), a1 = (f4v)(0.f), a2 = (f4v)(0.f);
  f4v a3 = (f4v)(0.f), a4 = (f4v)(0.f), a5 = (f4v)(0.f);

  int n = n_begin + r0;
  // 6 rows of stride 8 per iteration (48-row step)
  for (; n + 40 < n_end; n += 48) {
    f4v v0 = Hb[(size_t)n * 32 + d4];
    f4v v1 = Hb[(size_t)(n + 8) * 32 + d4];
    f4v v2 = Hb[(size_t)(n + 16) * 32 + d4];
    f4v v3 = Hb[(size_t)(n + 24) * 32 + d4];
    f4v v4 = Hb[(size_t)(n + 32) * 32 + d4];
    f4v v5 = Hb[(size_t)(n + 40) * 32 + d4];
    a0 += v0; a1 += v1; a2 += v2; a3 += v3; a4 += v4; a5 += v5;
  }
  for (; n < n_end; n += 8) {
    a0 += Hb[(size_t)n * 32 + d4];
  }
  a0 = ((a0 + a1) + (a2 + a3)) + (a4 + a5);

  __shared__ f4v smem[256];
  smem[t] = a0;
  __syncthreads();

  if (t < 32) {
    f4v sum = smem[t];
#pragma unroll
    for (int j = 1; j < 8; ++j) sum += smem[t + 32 * j];
    reinterpret_cast<f4v*>(partial)[((size_t)b * S_SLICES + s) * 32 + t] = sum;
  }
}

// ---------------------------------------------------------------------------
// Kernel 2: finalize. grid = B, block = 512.
//  - reduce S partials -> mean; gather 4 rows + ReLU; emb (640 f) in LDS
//  - matvec: 16 k-slices x 40 k, float4 W loads, LDS tree-reduce, ReLU, store
// ---------------------------------------------------------------------------
__global__ __launch_bounds__(512) void finalize_kernel(
    const float* __restrict__ H, const int* __restrict__ indice,
    const float* __restrict__ W, const float* __restrict__ partial,
    float* __restrict__ out) {
  const int b = blockIdx.x;
  const int t = threadIdx.x;

  __shared__ float emb[(PF + 1) * PD];  // 640 floats
  __shared__ f4v red[16][32];           // 8 KB

  // Gathered rows, ReLU-clamped: f = t>>7 (0..3), d = t&127
  {
    const int f = t >> 7;
    const int d = t & 127;
    const int idx = indice[b * PF + f];
    emb[f * PD + d] = fmaxf(H[((size_t)b * PN + (size_t)idx) * PD + d], 0.f);
  }
  // Mean row: first 128 threads reduce the S partials
  if (t < PD) {
    const float* p = partial + (size_t)b * S_SLICES * PD + t;
    float sum = 0.f;
#pragma unroll
    for (int s = 0; s < S_SLICES; ++s) sum += p[(size_t)s * PD];
    emb[PF * PD + t] = sum * (1.0f / (float)PN);
  }
  __syncthreads();

  // Matvec: thread (w, d4) accumulates k in [w*40, w*40+40) for 4 columns
  const int d4 = t & 31;
  const int w = t >> 5;  // 0..15
  const f4v* __restrict__ W4 = reinterpret_cast<const f4v*>(W);
  f4v acc = (f4v)(0.f);
  const int k0 = w * 40;
#pragma unroll
  for (int kk = 0; kk < 40; ++kk) {
    const int k = k0 + kk;
    acc += emb[k] * W4[(size_t)k * 32 + d4];
  }
  red[w][d4] = acc;
  __syncthreads();
  if (w < 8) red[w][d4] += red[w + 8][d4];
  __syncthreads();
  if (w < 4) red[w][d4] += red[w + 4][d4];
  __syncthreads();
  if (w < 2) red[w][d4] += red[w + 2][d4];
  __syncthreads();
  if (w == 0) {
    f4v r = red[0][d4] + red[1][d4];
    f4v o;
    o.x = fmaxf(r.x, 0.f); o.y = fmaxf(r.y, 0.f);
    o.z = fmaxf(r.z, 0.f); o.w = fmaxf(r.w, 0.f);
    reinterpret_cast<f4v*>(out)[(size_t)b * 32 + d4] = o;
  }
}

extern "C" void kernel_launch(void* const* d_in, const int* in_sizes, int n_in,
                              void* d_out, int out_size, void* d_ws, size_t ws_size,
                              hipStream_t stream) {
  const float* H = (const float*)d_in[0];
  const int* indice = (const int*)d_in[1];
  const float* W = (const float*)d_in[2];
  float* out = (float*)d_out;
  float* partial = (float*)d_ws;

  const int rows_per_slice = (PN + S_SLICES - 1) / S_SLICES;

  dim3 grid1(PB, S_SLICES);
  partial_sum_kernel<<<grid1, 256, 0, stream>>>(H, partial, rows_per_slice);
  finalize_kernel<<<PB, 512, 0, stream>>>(H, indice, W, partial, out);
}

// Round 7
// 57.075 us; speedup vs baseline: 1.0969x; 1.0969x over previous
//
#include <hip/hip_runtime.h>

// Problem constants (match reference): B=64, N=10000, D=128, F=4
#define PB 64
#define PN 10000
#define PD 128
#define PF 4
#define S_SLICES 32  // partial-sum slices over N; ws: 1 MB partial + 32 KB gacc

typedef float f4v __attribute__((ext_vector_type(4)));

// ---------------------------------------------------------------------------
// Kernel 1: grid (B, S_SLICES+1), block 256.
//  s < S_SLICES : partial mean-sum for the (b,s) N-slice (nontemporal 16B
//                 loads, 6 in flight/thread), write partial[b][s][0:128].
//  s == S_SLICES: gather block — runs in the stream's shadow. Gather 4
//                 indexed rows, ReLU, matvec vs W[0:512,:] -> gacc[b][0:128].
// ---------------------------------------------------------------------------
__global__ __launch_bounds__(256) void partial_sum_kernel(
    const float* __restrict__ H, const int* __restrict__ indice,
    const float* __restrict__ W, float* __restrict__ partial,
    float* __restrict__ gacc, int rows_per_slice) {
  const int b = blockIdx.x;
  const int s = blockIdx.y;
  const int t = threadIdx.x;
  const int d4 = t & 31;

  if (s < S_SLICES) {
    const int r0 = t >> 5;
    const int n_begin = s * rows_per_slice;
    int n_end = n_begin + rows_per_slice;
    if (n_end > PN) n_end = PN;

    const f4v* __restrict__ Hb =
        reinterpret_cast<const f4v*>(H) + (size_t)b * PN * (PD / 4);

    f4v a0 = (f4v)(0.f), a1 = (f4v)(0.f), a2 = (f4v)(0.f);
    f4v a3 = (f4v)(0.f), a4 = (f4v)(0.f), a5 = (f4v)(0.f);

    int n = n_begin + r0;
    for (; n + 40 < n_end; n += 48) {
      f4v v0 = __builtin_nontemporal_load(Hb + (size_t)n * 32 + d4);
      f4v v1 = __builtin_nontemporal_load(Hb + (size_t)(n + 8) * 32 + d4);
      f4v v2 = __builtin_nontemporal_load(Hb + (size_t)(n + 16) * 32 + d4);
      f4v v3 = __builtin_nontemporal_load(Hb + (size_t)(n + 24) * 32 + d4);
      f4v v4 = __builtin_nontemporal_load(Hb + (size_t)(n + 32) * 32 + d4);
      f4v v5 = __builtin_nontemporal_load(Hb + (size_t)(n + 40) * 32 + d4);
      a0 += v0; a1 += v1; a2 += v2; a3 += v3; a4 += v4; a5 += v5;
    }
    for (; n < n_end; n += 8) {
      a0 += __builtin_nontemporal_load(Hb + (size_t)n * 32 + d4);
    }
    a0 = ((a0 + a1) + (a2 + a3)) + (a4 + a5);

    __shared__ f4v smem[256];
    smem[t] = a0;
    __syncthreads();
    if (t < 32) {
      f4v sum = smem[t];
#pragma unroll
      for (int j = 1; j < 8; ++j) sum += smem[t + 32 * j];
      reinterpret_cast<f4v*>(partial)[((size_t)b * S_SLICES + s) * 32 + t] = sum;
    }
    return;
  }

  // ---- gather block: G·W_g for k in [0, 512) ----
  __shared__ float g_emb[PF * PD];  // 512 floats
  __shared__ f4v red[8][32];        // 4 KB
  {
    int id = t;
#pragma unroll
    for (int rep = 0; rep < 2; ++rep, id += 256) {
      const int f = id >> 7;        // 0..3
      const int d = id & (PD - 1);  // 0..127
      const int idx = indice[b * PF + f];
      g_emb[f * PD + d] = fmaxf(H[((size_t)b * PN + (size_t)idx) * PD + d], 0.f);
    }
  }
  __syncthreads();

  const f4v* __restrict__ W4 = reinterpret_cast<const f4v*>(W);
  const int w = t >> 5;  // 0..7, 64 k each
  f4v acc = (f4v)(0.f);
  const int k0 = w * 64;
#pragma unroll
  for (int kk = 0; kk < 64; ++kk) {
    const int k = k0 + kk;
    acc += g_emb[k] * W4[(size_t)k * 32 + d4];
  }
  red[w][d4] = acc;
  __syncthreads();
  if (w < 4) red[w][d4] += red[w + 4][d4];
  __syncthreads();
  if (w < 2) red[w][d4] += red[w + 2][d4];
  __syncthreads();
  if (w == 0) {
    reinterpret_cast<f4v*>(gacc)[(size_t)b * 32 + d4] = red[0][d4] + red[1][d4];
  }
}

// ---------------------------------------------------------------------------
// Kernel 2: small finalize. grid = B, block = 128.
//  mean-reduce partials, matvec vs W[512:640,:], add gacc, ReLU, store.
// ---------------------------------------------------------------------------
__global__ __launch_bounds__(128) void finalize_kernel(
    const float* __restrict__ W, const float* __restrict__ partial,
    const float* __restrict__ gacc, float* __restrict__ out) {
  const int b = blockIdx.x;
  const int t = threadIdx.x;
  const int d4 = t & 31;
  const int w = t >> 5;  // 0..3

  __shared__ float meanrow[PD];
  __shared__ f4v red[4][32];

  // mean over N for column t
  {
    const float* p = partial + (size_t)b * S_SLICES * PD + t;
    float sum = 0.f;
#pragma unroll
    for (int ss = 0; ss < S_SLICES; ++ss) sum += p[(size_t)ss * PD];
    meanrow[t] = sum * (1.0f / (float)PN);
  }
  __syncthreads();

  // matvec over k in [512, 640): w-slice of 32 k
  const f4v* __restrict__ W4 = reinterpret_cast<const f4v*>(W);
  f4v acc = (f4v)(0.f);
  const int k0 = w * 32;
#pragma unroll
  for (int kk = 0; kk < 32; ++kk) {
    const int k = k0 + kk;
    acc += meanrow[k] * W4[(size_t)(PF * PD + k) * 32 + d4];
  }
  red[w][d4] = acc;
  __syncthreads();
  if (w < 2) red[w][d4] += red[w + 2][d4];
  __syncthreads();
  if (w == 0) {
    f4v r = red[0][d4] + red[1][d4] +
            reinterpret_cast<const f4v*>(gacc)[(size_t)b * 32 + d4];
    f4v o;
    o.x = fmaxf(r.x, 0.f); o.y = fmaxf(r.y, 0.f);
    o.z = fmaxf(r.z, 0.f); o.w = fmaxf(r.w, 0.f);
    reinterpret_cast<f4v*>(out)[(size_t)b * 32 + d4] = o;
  }
}

// ---------------------------------------------------------------------------
// Fallback finalize (if ws too small for gacc): full 640-k matvec. grid B,512.
// ---------------------------------------------------------------------------
__global__ __launch_bounds__(512) void finalize_full_kernel(
    const float* __restrict__ H, const int* __restrict__ indice,
    const float* __restrict__ W, const float* __restrict__ partial,
    float* __restrict__ out) {
  const int b = blockIdx.x;
  const int t = threadIdx.x;
  __shared__ float emb[(PF + 1) * PD];
  __shared__ f4v red[16][32];
  {
    const int f = t >> 7;
    const int d = t & 127;
    const int idx = indice[b * PF + f];
    emb[f * PD + d] = fmaxf(H[((size_t)b * PN + (size_t)idx) * PD + d], 0.f);
  }
  if (t < PD) {
    const float* p = partial + (size_t)b * S_SLICES * PD + t;
    float sum = 0.f;
#pragma unroll
    for (int s = 0; s < S_SLICES; ++s) sum += p[(size_t)s * PD];
    emb[PF * PD + t] = sum * (1.0f / (float)PN);
  }
  __syncthreads();
  const int d4 = t & 31;
  const int w = t >> 5;
  const f4v* __restrict__ W4 = reinterpret_cast<const f4v*>(W);
  f4v acc = (f4v)(0.f);
  const int k0 = w * 40;
#pragma unroll
  for (int kk = 0; kk < 40; ++kk) {
    const int k = k0 + kk;
    acc += emb[k] * W4[(size_t)k * 32 + d4];
  }
  red[w][d4] = acc;
  __syncthreads();
  if (w < 8) red[w][d4] += red[w + 8][d4];
  __syncthreads();
  if (w < 4) red[w][d4] += red[w + 4][d4];
  __syncthreads();
  if (w < 2) red[w][d4] += red[w + 2][d4];
  __syncthreads();
  if (w == 0) {
    f4v r = red[0][d4] + red[1][d4];
    f4v o;
    o.x = fmaxf(r.x, 0.f); o.y = fmaxf(r.y, 0.f);
    o.z = fmaxf(r.z, 0.f); o.w = fmaxf(r.w, 0.f);
    reinterpret_cast<f4v*>(out)[(size_t)b * 32 + d4] = o;
  }
}

__global__ __launch_bounds__(256) void partial_only_kernel(
    const float* __restrict__ H, float* __restrict__ partial,
    int rows_per_slice) {
  const int b = blockIdx.x;
  const int s = blockIdx.y;
  const int t = threadIdx.x;
  const int d4 = t & 31;
  const int r0 = t >> 5;
  const int n_begin = s * rows_per_slice;
  int n_end = n_begin + rows_per_slice;
  if (n_end > PN) n_end = PN;
  const f4v* __restrict__ Hb =
      reinterpret_cast<const f4v*>(H) + (size_t)b * PN * (PD / 4);
  f4v a0 = (f4v)(0.f), a1 = (f4v)(0.f), a2 = (f4v)(0.f);
  f4v a3 = (f4v)(0.f), a4 = (f4v)(0.f), a5 = (f4v)(0.f);
  int n = n_begin + r0;
  for (; n + 40 < n_end; n += 48) {
    f4v v0 = __builtin_nontemporal_load(Hb + (size_t)n * 32 + d4);
    f4v v1 = __builtin_nontemporal_load(Hb + (size_t)(n + 8) * 32 + d4);
    f4v v2 = __builtin_nontemporal_load(Hb + (size_t)(n + 16) * 32 + d4);
    f4v v3 = __builtin_nontemporal_load(Hb + (size_t)(n + 24) * 32 + d4);
    f4v v4 = __builtin_nontemporal_load(Hb + (size_t)(n + 32) * 32 + d4);
    f4v v5 = __builtin_nontemporal_load(Hb + (size_t)(n + 40) * 32 + d4);
    a0 += v0; a1 += v1; a2 += v2; a3 += v3; a4 += v4; a5 += v5;
  }
  for (; n < n_end; n += 8) a0 += __builtin_nontemporal_load(Hb + (size_t)n * 32 + d4);
  a0 = ((a0 + a1) + (a2 + a3)) + (a4 + a5);
  __shared__ f4v smem[256];
  smem[t] = a0;
  __syncthreads();
  if (t < 32) {
    f4v sum = smem[t];
#pragma unroll
    for (int j = 1; j < 8; ++j) sum += smem[t + 32 * j];
    reinterpret_cast<f4v*>(partial)[((size_t)b * S_SLICES + s) * 32 + t] = sum;
  }
}

extern "C" void kernel_launch(void* const* d_in, const int* in_sizes, int n_in,
                              void* d_out, int out_size, void* d_ws, size_t ws_size,
                              hipStream_t stream) {
  const float* H = (const float*)d_in[0];
  const int* indice = (const int*)d_in[1];
  const float* W = (const float*)d_in[2];
  float* out = (float*)d_out;
  float* partial = (float*)d_ws;

  const size_t partial_bytes = (size_t)PB * S_SLICES * PD * sizeof(float);  // 1 MB
  const size_t gacc_bytes = (size_t)PB * PD * sizeof(float);                // 32 KB
  const int rows_per_slice = (PN + S_SLICES - 1) / S_SLICES;

  if (ws_size >= partial_bytes + gacc_bytes) {
    float* gacc = (float*)((char*)d_ws + partial_bytes);
    dim3 grid1(PB, S_SLICES + 1);
    partial_sum_kernel<<<grid1, 256, 0, stream>>>(H, indice, W, partial, gacc,
                                                  rows_per_slice);
    finalize_kernel<<<PB, 128, 0, stream>>>(W, partial, gacc, out);
  } else {
    dim3 grid1(PB, S_SLICES);
    partial_only_kernel<<<grid1, 256, 0, stream>>>(H, partial, rows_per_slice);
    finalize_full_kernel<<<PB, 512, 0, stream>>>(H, indice, W, partial, out);
  }
}